// Round 5
// baseline (148.556 us; speedup 1.0000x reference)
//
#include <hip/hip_runtime.h>
#include <math.h>

#define NN 10000
#define EE 640000
#define DD 256
#define HB 32             // histogram/build blocks
#define EPB (EE / HB)     // 20000 edges per block
#define CAP 128           // ELL row capacity (deg ~ Poisson(64))
#define NTHR 512
#define NWAVE 8
#define CONVB 512
#define PB 20             // prefix blocks inside K2
#define K2B 256           // K2 total blocks

// ws float-offset layout
#define OFF_DINV   0
#define OFF_XW     (NN)
#define OFF_C1     (2*NN)
#define OFF_C2     (3*NN)
#define OFF_C3     (4*NN)
#define OFF_CNT    (5*NN)             // int[NN]
#define OFF_XP     (6*NN)             // xp1[0..143], regAcc[144], done-ctr int at [152]
#define OFF_CNTP   (6*NN + 160)       // int[HB*NN]
#define OFF_WDEGP  (OFF_CNTP + HB*NN) // float[HB*NN]
#define OFF_BASE   (OFF_WDEGP + HB*NN)// int[HB*NN]
#define OFF_SLOTS  (OFF_BASE + HB*NN) // uint2[NN*CAP] (even float offset -> 8B aligned)

// K1: per-block LDS histogram of counts + weighted degree over edge slice.
//     Block 0 also zeroes xp1/regAcc/done-counter for this call.
__global__ __launch_bounds__(NTHR) void k1_hist(
    const int* __restrict__ dst, const float* __restrict__ ew, float* __restrict__ ws)
{
    __shared__ int   s_cnt[NN];    // 40 KB
    __shared__ float s_wdeg[NN];   // 40 KB
    int tid = threadIdx.x, bid = blockIdx.x;
    if (bid == 0 && tid < 160) ws[OFF_XP + tid] = 0.0f;   // covers ctr bits too
    for (int i = tid; i < NN; i += NTHR) { s_cnt[i] = 0; s_wdeg[i] = 0.f; }
    __syncthreads();
    int base = bid * EPB;
    for (int k = tid; k < EPB; k += NTHR) {
        int e = base + k;
        int d = dst[e];
        atomicAdd(&s_cnt[d], 1);
        atomicAdd(&s_wdeg[d], ew[e]);
    }
    __syncthreads();
    int*   cp = (int*)ws + OFF_CNTP + bid * NN;
    float* wp = ws + OFF_WDEGP + bid * NN;
    for (int i = tid; i < NN; i += NTHR) { cp[i] = s_cnt[i]; wp[i] = s_wdeg[i]; }
}

// K2: blocks 0..PB-1: per-node exclusive prefix over HB partials -> base, cnt;
//                     dinv = (1 + sum wdeg)^(-1/2).
//     blocks PB.. : xw = x @ W1, wave per row, next-row prefetch, no LDS.
__global__ __launch_bounds__(NTHR) void k2_prefix_xw(
    const float* __restrict__ x, const float* __restrict__ W1, float* __restrict__ ws)
{
    int tid = threadIdx.x, bid = blockIdx.x;
    if (bid < PB) {
        int gt = bid * NTHR + tid;
        if (gt >= NN) return;
        const int* cntp = (const int*)ws + OFF_CNTP;
        int* basep = (int*)ws + OFF_BASE;
        int run = 0;
        #pragma unroll
        for (int b = 0; b < HB; b++) {
            int v = cntp[b * NN + gt];
            basep[b * NN + gt] = run;
            run += v;
        }
        ((int*)ws)[OFF_CNT + gt] = min(run, CAP);
        const float* wd = ws + OFF_WDEGP;
        float s = 1.0f;                       // self-loop weight
        #pragma unroll
        for (int b = 0; b < HB; b++) s += wd[b * NN + gt];
        ws[OFF_DINV + gt] = (s > 0.f) ? 1.0f / sqrtf(s) : 0.f;
    } else {
        int lane = tid & 63, wv = tid >> 6;
        const int stride = (K2B - PB) * NWAVE;          // 1888 waves
        float* xw = ws + OFF_XW;
        float4 wreg = reinterpret_cast<const float4*>(W1)[lane];
        int row = (bid - PB) * NWAVE + wv;
        if (row >= NN) return;
        float4 a = reinterpret_cast<const float4*>(x + (size_t)row * DD)[lane];
        while (true) {
            int nrow = row + stride;
            float4 an;
            if (nrow < NN) an = reinterpret_cast<const float4*>(x + (size_t)nrow * DD)[lane];
            float v = a.x*wreg.x + a.y*wreg.y + a.z*wreg.z + a.w*wreg.w;
            #pragma unroll
            for (int off = 32; off; off >>= 1) v += __shfl_xor(v, off);
            if (lane == 0) xw[row] = v;
            if (nrow >= NN) break;
            a = an; row = nrow;
        }
    }
}

// K3: rank-scatter edges into ELL slots with pre-normalized value
//     val = ew * dinv[src] * dinv[dst].
__global__ __launch_bounds__(NTHR) void k3_build(
    const int* __restrict__ src, const int* __restrict__ dst,
    const float* __restrict__ ew, float* __restrict__ ws)
{
    __shared__ int s_rank[NN];     // 40 KB
    int tid = threadIdx.x, bid = blockIdx.x;
    for (int i = tid; i < NN; i += NTHR) s_rank[i] = 0;
    __syncthreads();
    const float* dinv = ws + OFF_DINV;
    const int* basep = (const int*)ws + OFF_BASE + bid * NN;
    uint2* slots = (uint2*)(ws + OFF_SLOTS);
    int base = bid * EPB;
    for (int k = tid; k < EPB; k += NTHR) {
        int e = base + k;
        int d = dst[e], s = src[e];
        int r = atomicAdd(&s_rank[d], 1);
        int off = basep[d] + r;
        if (off < CAP) {
            uint2 pk;
            pk.x = (unsigned)s;
            pk.y = __float_as_uint(ew[e] * dinv[s] * dinv[d]);
            slots[(size_t)d * CAP + off] = pk;
        }
    }
}

// K4/K5/K6: gather SpMV, wave per row:
//   c[i] = M * (sum_slots val*hin[src] + dinv[i]^2 * hin[i]) + B
// POOL: fuse DiffPool stage 1; the LAST block to finish runs stages 2..4.
template <bool POOL>
__global__ __launch_bounds__(NTHR) void k_conv(
    const float* __restrict__ hin, float* __restrict__ cout,
    const float* __restrict__ multp, const float* __restrict__ biasp,
    const float* __restrict__ P1, const float* __restrict__ c1,
    const float* __restrict__ c2, const float* __restrict__ P2,
    const float* __restrict__ P3, float* __restrict__ ws, float* __restrict__ out)
{
    int tid = threadIdx.x, bid = blockIdx.x;
    int lane = tid & 63, wv = tid >> 6;
    const uint2* slots = (const uint2*)(ws + OFF_SLOTS);
    const int* cnt = (const int*)ws + OFF_CNT;
    const float* dinv = ws + OFF_DINV;
    float M = multp ? *multp : 1.0f;
    float B = *biasp;
    float a0 = 0.f, a1 = 0.f, a2 = 0.f, ent = 0.f;
    int stride = gridDim.x * NWAVE;
    for (int row = bid * NWAVE + wv; row < NN; row += stride) {
        int c = cnt[row];
        float acc = 0.f;
        if (lane < c) {
            uint2 pk = slots[(size_t)row * CAP + lane];
            acc += __uint_as_float(pk.y) * hin[pk.x];
        }
        if (lane + 64 < c) {
            uint2 pk = slots[(size_t)row * CAP + lane + 64];
            acc += __uint_as_float(pk.y) * hin[pk.x];
        }
        #pragma unroll
        for (int off = 32; off; off >>= 1) acc += __shfl_xor(acc, off);
        float di = dinv[row];
        float cv = M * (acc + di * di * hin[row]) + B;
        if (lane == 0) cout[row] = cv;
        if constexpr (POOL) {
            float v = (lane < 48) ? P1[(size_t)row * 48 + lane] : -1e30f;
            float mx = v;
            #pragma unroll
            for (int off = 32; off; off >>= 1) mx = fmaxf(mx, __shfl_xor(mx, off));
            float e = (lane < 48) ? expf(v - mx) : 0.f;
            float sum = e;
            #pragma unroll
            for (int off = 32; off; off >>= 1) sum += __shfl_xor(sum, off);
            float p = e / sum;
            if (lane < 48) {
                ent -= p * logf(p + 1e-12f);
                a0 += p * c1[row];
                a1 += p * c2[row];
                a2 += p * cv;               // cv valid in all lanes
            }
        }
    }
    if constexpr (POOL) {
        __shared__ float part[NWAVE][48][3];
        __shared__ float entW[NWAVE];
        __shared__ int sh_last;
        #pragma unroll
        for (int off = 32; off; off >>= 1) ent += __shfl_xor(ent, off);
        if (lane == 0) entW[wv] = ent;
        if (lane < 48) { part[wv][lane][0] = a0; part[wv][lane][1] = a1; part[wv][lane][2] = a2; }
        __syncthreads();
        float* xp1 = ws + OFF_XP;
        if (tid < 144) {
            int j = tid / 3, col = tid % 3;
            float s = 0.f;
            #pragma unroll
            for (int w = 0; w < NWAVE; w++) s += part[w][j][col];
            atomicAdd(&xp1[j * 3 + col], s);
        }
        if (tid == 0) {
            float s = 0.f;
            #pragma unroll
            for (int w = 0; w < NWAVE; w++) s += entW[w];
            atomicAdd(&xp1[144], s);
        }
        // ---- last-block epilogue: pool stages 2..4 ----
        if (tid == 0) {
            __threadfence();
            int old = atomicAdd((int*)ws + OFF_XP + 152, 1);
            sh_last = (old == (int)gridDim.x - 1) ? 1 : 0;
        }
        __syncthreads();
        if (sh_last) {
            __shared__ float shXp[145];
            __shared__ float S2[48][12], xp2[12][3];
            __shared__ float S3[12][4], xp3[4][3];
            __shared__ float ent2, ent3;
            if (tid < 145) shXp[tid] = atomicAdd(&xp1[tid], 0.0f);  // coherent read
            if (tid == 0) { ent2 = 0.f; ent3 = 0.f; }
            __syncthreads();
            if (tid < 48) {
                float v[12], mx = -1e30f;
                #pragma unroll
                for (int j = 0; j < 12; j++) { v[j] = P2[tid * 12 + j]; mx = fmaxf(mx, v[j]); }
                float s = 0.f;
                #pragma unroll
                for (int j = 0; j < 12; j++) { v[j] = expf(v[j] - mx); s += v[j]; }
                float e = 0.f;
                #pragma unroll
                for (int j = 0; j < 12; j++) {
                    float p = v[j] / s; S2[tid][j] = p; e -= p * logf(p + 1e-12f);
                }
                atomicAdd(&ent2, e);
            }
            __syncthreads();
            if (tid < 36) {
                int j = tid / 3, col = tid % 3;
                float s = 0.f;
                for (int i = 0; i < 48; i++) s += S2[i][j] * shXp[i * 3 + col];
                xp2[j][col] = s;
            }
            __syncthreads();
            if (tid < 12) {
                float v[4], mx = -1e30f;
                #pragma unroll
                for (int j = 0; j < 4; j++) { v[j] = P3[tid * 4 + j]; mx = fmaxf(mx, v[j]); }
                float s = 0.f;
                #pragma unroll
                for (int j = 0; j < 4; j++) { v[j] = expf(v[j] - mx); s += v[j]; }
                float e = 0.f;
                #pragma unroll
                for (int j = 0; j < 4; j++) {
                    float p = v[j] / s; S3[tid][j] = p; e -= p * logf(p + 1e-12f);
                }
                atomicAdd(&ent3, e);
            }
            __syncthreads();
            if (tid < 12) {
                int j = tid / 3, col = tid % 3;
                float s = 0.f;
                for (int i = 0; i < 12; i++) s += S3[i][j] * xp2[i][col];
                xp3[j][col] = s;
            }
            __syncthreads();
            if (tid == 0) {
                float o0 = 0.f, o1 = 0.f, o2 = 0.f;
                for (int i = 0; i < 4; i++) {
                    o0 += xp3[i][0]; o1 += xp3[i][1]; o2 += xp3[i][2];
                }
                // stage-4: width-1 softmax -> p==1, entropy==0 in fp32
                float reg = shXp[144] / (float)NN + ent2 / 48.f + ent3 / 12.f;
                out[0] = o0; out[1] = o1; out[2] = o2; out[3] = reg;
            }
        }
    }
}

extern "C" void kernel_launch(void* const* d_in, const int* in_sizes, int n_in,
                              void* d_out, int out_size, void* d_ws, size_t ws_size,
                              hipStream_t stream) {
    const float* x  = (const float*)d_in[0];
    const int*   ei = (const int*)d_in[1];
    const float* ea = (const float*)d_in[2];
    // d_in[3] = adj — unused by the reference.
    const float* W1 = (const float*)d_in[4];
    const float* b1 = (const float*)d_in[5];
    const float* W2 = (const float*)d_in[6];
    const float* b2 = (const float*)d_in[7];
    const float* P1 = (const float*)d_in[8];
    const float* P2 = (const float*)d_in[9];
    const float* P3 = (const float*)d_in[10];
    // d_in[11] = P4 — width-1 softmax, handled analytically.
    const int* src = ei;
    const int* dst = ei + EE;
    float* ws  = (float*)d_ws;
    float* out = (float*)d_out;

    float* xw = ws + OFF_XW;
    float* c1 = ws + OFF_C1;
    float* c2 = ws + OFF_C2;
    float* c3 = ws + OFF_C3;

    k1_hist<<<HB, NTHR, 0, stream>>>(dst, ea, ws);
    k2_prefix_xw<<<K2B, NTHR, 0, stream>>>(x, W1, ws);
    k3_build<<<HB, NTHR, 0, stream>>>(src, dst, ea, ws);
    k_conv<false><<<CONVB, NTHR, 0, stream>>>(xw, c1, nullptr, b1,
                                              nullptr, nullptr, nullptr, nullptr, nullptr, ws, nullptr);
    k_conv<false><<<CONVB, NTHR, 0, stream>>>(c1, c2, W2, b2,
                                              nullptr, nullptr, nullptr, nullptr, nullptr, ws, nullptr);
    k_conv<true ><<<CONVB, NTHR, 0, stream>>>(c2, c3, W2, b2,
                                              P1, c1, c2, P2, P3, ws, out);
}

// Round 6
// 87.049 us; speedup vs baseline: 1.7066x; 1.7066x over previous
//
#include <hip/hip_runtime.h>
#include <math.h>

#define NN 10000
#define EE 640000
#define DD 256
#define SB 256            // scatter blocks (full chip), EE/SB = 2500 edges each
#define EPB (EE / SB)
#define NTHR 512
#define RB 157            // reduce blocks: 157*64 = 10048 >= NN

// ws float-offset layout
#define OFF_DINV 0
#define OFF_XW   (NN)
#define OFF_C1   (2*NN)
#define OFF_C2   (3*NN)
#define OFF_U0   (4*NN)
#define OFF_U1   (5*NN)
#define OFF_U2   (6*NN)
#define OFF_XP   (7*NN)         // [0..143] xp1, [144] regAcc, [152] int done-ctr
#define OFF_PART (7*NN + 160)   // SB*NN floats (10.24 MB), reused each pass

// K1: deg scatter (LDS acc, coalesced flush to partials) + xw = x@W1 fused.
__global__ __launch_bounds__(NTHR) void k1_deg_xw(
    const int* __restrict__ dst, const float* __restrict__ ew,
    const float* __restrict__ x, const float* __restrict__ W1,
    float* __restrict__ ws)
{
    __shared__ float acc[NN];    // 40 KB
    int tid = threadIdx.x, bid = blockIdx.x;
    int lane = tid & 63, wv = tid >> 6;
    if (bid == 0 && tid < 160) ws[OFF_XP + tid] = 0.f;   // xp1 + reg + done-ctr
    for (int i = tid; i < NN; i += NTHR) acc[i] = 0.f;
    __syncthreads();
    {   // xw: wave per row, float4 dot + butterfly
        float4 wreg = reinterpret_cast<const float4*>(W1)[lane];
        float* xw = ws + OFF_XW;
        for (int row = bid * 8 + wv; row < NN; row += SB * 8) {
            float4 a = reinterpret_cast<const float4*>(x + (size_t)row * DD)[lane];
            float v = a.x*wreg.x + a.y*wreg.y + a.z*wreg.z + a.w*wreg.w;
            #pragma unroll
            for (int off = 32; off; off >>= 1) v += __shfl_xor(v, off);
            if (lane == 0) xw[row] = v;
        }
    }
    int base = bid * EPB;
    for (int k = tid; k < EPB; k += NTHR) {
        int e = base + k;
        atomicAdd(&acc[dst[e]], ew[e]);
    }
    __syncthreads();
    float* p = ws + OFF_PART + (size_t)bid * NN;
    for (int i = tid; i < NN; i += NTHR) p[i] = acc[i];
}

// K2: reduce deg partials -> dinv = (1+deg)^(-1/2); u0 = dinv*xw.
// Block: 64 nodes x 8 slices of SB/8=32 partials; all loads wave-coalesced.
__global__ __launch_bounds__(NTHR) void k2_dinv(float* __restrict__ ws)
{
    __shared__ float red[8][64];
    int tid = threadIdx.x, bid = blockIdx.x;
    int nl = tid & 63, sl = tid >> 6;
    int node = bid * 64 + nl;
    const float* part = ws + OFF_PART;
    float s = 0.f;
    if (node < NN) {
        #pragma unroll 8
        for (int it = 0; it < SB / 8; ++it)
            s += part[(size_t)(sl * (SB / 8) + it) * NN + node];
    }
    red[sl][nl] = s;
    __syncthreads();
    if (tid < 64 && node < NN) {
        float tot = 1.f;                   // self-loop weight
        #pragma unroll
        for (int q = 0; q < 8; ++q) tot += red[q][tid];
        float di = (tot > 0.f) ? 1.0f / sqrtf(tot) : 0.f;
        ws[OFF_DINV + node] = di;
        ws[OFF_U0 + node] = di * ws[OFF_XW + node];
    }
}

// K3/K5/K7: edge scatter of ew[e]*u[src[e]] into LDS by dst, coalesced flush.
__global__ __launch_bounds__(NTHR) void k_scat(
    const int* __restrict__ src, const int* __restrict__ dst,
    const float* __restrict__ ew, const float* __restrict__ u,
    float* __restrict__ ws)
{
    __shared__ float acc[NN];
    int tid = threadIdx.x, bid = blockIdx.x;
    for (int i = tid; i < NN; i += NTHR) acc[i] = 0.f;
    __syncthreads();
    int base = bid * EPB;
    for (int k = tid; k < EPB; k += NTHR) {
        int e = base + k;
        atomicAdd(&acc[dst[e]], ew[e] * u[src[e]]);
    }
    __syncthreads();
    float* p = ws + OFF_PART + (size_t)bid * NN;
    for (int i = tid; i < NN; i += NTHR) p[i] = acc[i];
}

// K4/K6: reduce conv partials: c = M*di*(sum + di*hin) + B ; u = di*c.
__global__ __launch_bounds__(NTHR) void k_red_conv(
    const float* __restrict__ hin, const float* __restrict__ multp,
    const float* __restrict__ biasp, float* __restrict__ cout,
    float* __restrict__ uout, float* __restrict__ ws)
{
    __shared__ float red[8][64];
    int tid = threadIdx.x, bid = blockIdx.x;
    int nl = tid & 63, sl = tid >> 6;
    int node = bid * 64 + nl;
    const float* part = ws + OFF_PART;
    float s = 0.f;
    if (node < NN) {
        #pragma unroll 8
        for (int it = 0; it < SB / 8; ++it)
            s += part[(size_t)(sl * (SB / 8) + it) * NN + node];
    }
    red[sl][nl] = s;
    __syncthreads();
    if (tid < 64 && node < NN) {
        float tot = 0.f;
        #pragma unroll
        for (int q = 0; q < 8; ++q) tot += red[q][tid];
        float di = ws[OFF_DINV + node];
        float M = multp ? *multp : 1.0f;
        float cv = M * di * (tot + di * hin[node]) + *biasp;
        cout[node] = cv;
        uout[node] = di * cv;
    }
}

// K8: reduce -> c3 (block-local), pool stage 1 for the block's 64 rows,
//     last-done block runs pool stages 2..4 and writes out.
__global__ __launch_bounds__(NTHR) void k8_final(
    const float* __restrict__ hin,                         // c2
    const float* __restrict__ multp, const float* __restrict__ biasp,
    const float* __restrict__ c1, const float* __restrict__ c2,
    const float* __restrict__ P1, const float* __restrict__ P2,
    const float* __restrict__ P3, float* __restrict__ ws, float* __restrict__ out)
{
    __shared__ float red[8][64];
    __shared__ float s_c3[64];
    __shared__ float part[8][48][3];
    __shared__ float entW[8];
    __shared__ int sh_last;
    int tid = threadIdx.x, bid = blockIdx.x;
    int lane = tid & 63, wv = tid >> 6;
    int node = bid * 64 + lane;
    const float* partg = ws + OFF_PART;
    float s = 0.f;
    if (node < NN) {
        #pragma unroll 8
        for (int it = 0; it < SB / 8; ++it)
            s += partg[(size_t)(wv * (SB / 8) + it) * NN + node];
    }
    red[wv][lane] = s;
    __syncthreads();
    if (tid < 64) {
        float cv = 0.f;
        if (node < NN) {
            float tot = 0.f;
            #pragma unroll
            for (int q = 0; q < 8; ++q) tot += red[q][tid];
            float di = ws[OFF_DINV + node];
            cv = (*multp) * di * (tot + di * hin[node]) + *biasp;
        }
        s_c3[tid] = cv;
    }
    __syncthreads();
    // ---- pool stage 1 over this block's rows: wave wv -> rows wv*8..wv*8+7 ----
    float a0 = 0.f, a1 = 0.f, a2 = 0.f, ent = 0.f;
    for (int j = 0; j < 8; ++j) {
        int rl = wv * 8 + j;
        int row = bid * 64 + rl;
        if (row >= NN) break;                        // wave-uniform
        float v = (lane < 48) ? P1[(size_t)row * 48 + lane] : -1e30f;
        float mx = v;
        #pragma unroll
        for (int off = 32; off; off >>= 1) mx = fmaxf(mx, __shfl_xor(mx, off));
        float e = (lane < 48) ? expf(v - mx) : 0.f;
        float sum = e;
        #pragma unroll
        for (int off = 32; off; off >>= 1) sum += __shfl_xor(sum, off);
        float p = e / sum;
        if (lane < 48) {
            ent -= p * logf(p + 1e-12f);
            a0 += p * c1[row];
            a1 += p * c2[row];
            a2 += p * s_c3[rl];
        }
    }
    #pragma unroll
    for (int off = 32; off; off >>= 1) ent += __shfl_xor(ent, off);
    if (lane == 0) entW[wv] = ent;
    if (lane < 48) { part[wv][lane][0] = a0; part[wv][lane][1] = a1; part[wv][lane][2] = a2; }
    __syncthreads();
    float* xp1 = ws + OFF_XP;
    if (tid < 144) {
        int j = tid / 3, col = tid % 3;
        float sp = 0.f;
        #pragma unroll
        for (int w = 0; w < 8; ++w) sp += part[w][j][col];
        atomicAdd(&xp1[j * 3 + col], sp);
    }
    if (tid == 0) {
        float sp = 0.f;
        #pragma unroll
        for (int w = 0; w < 8; ++w) sp += entW[w];
        atomicAdd(&xp1[144], sp);
    }
    // ---- last-block epilogue: pool stages 2..4 ----
    if (tid == 0) {
        __threadfence();
        int old = atomicAdd((int*)ws + OFF_XP + 152, 1);
        sh_last = (old == (int)gridDim.x - 1) ? 1 : 0;
    }
    __syncthreads();
    if (sh_last) {
        __shared__ float shXp[145];
        __shared__ float S2[48][12], xp2[12][3];
        __shared__ float S3[12][4], xp3[4][3];
        __shared__ float ent2, ent3;
        if (tid < 145) shXp[tid] = atomicAdd(&xp1[tid], 0.0f);  // coherent read
        if (tid == 0) { ent2 = 0.f; ent3 = 0.f; }
        __syncthreads();
        if (tid < 48) {
            float v[12], mx = -1e30f;
            #pragma unroll
            for (int j = 0; j < 12; j++) { v[j] = P2[tid * 12 + j]; mx = fmaxf(mx, v[j]); }
            float sm = 0.f;
            #pragma unroll
            for (int j = 0; j < 12; j++) { v[j] = expf(v[j] - mx); sm += v[j]; }
            float e = 0.f;
            #pragma unroll
            for (int j = 0; j < 12; j++) {
                float p = v[j] / sm; S2[tid][j] = p; e -= p * logf(p + 1e-12f);
            }
            atomicAdd(&ent2, e);
        }
        __syncthreads();
        if (tid < 36) {
            int j = tid / 3, col = tid % 3;
            float sm = 0.f;
            for (int i = 0; i < 48; i++) sm += S2[i][j] * shXp[i * 3 + col];
            xp2[j][col] = sm;
        }
        __syncthreads();
        if (tid < 12) {
            float v[4], mx = -1e30f;
            #pragma unroll
            for (int j = 0; j < 4; j++) { v[j] = P3[tid * 4 + j]; mx = fmaxf(mx, v[j]); }
            float sm = 0.f;
            #pragma unroll
            for (int j = 0; j < 4; j++) { v[j] = expf(v[j] - mx); sm += v[j]; }
            float e = 0.f;
            #pragma unroll
            for (int j = 0; j < 4; j++) {
                float p = v[j] / sm; S3[tid][j] = p; e -= p * logf(p + 1e-12f);
            }
            atomicAdd(&ent3, e);
        }
        __syncthreads();
        if (tid < 12) {
            int j = tid / 3, col = tid % 3;
            float sm = 0.f;
            for (int i = 0; i < 12; i++) sm += S3[i][j] * xp2[i][col];
            xp3[j][col] = sm;
        }
        __syncthreads();
        if (tid == 0) {
            float o0 = 0.f, o1 = 0.f, o2 = 0.f;
            for (int i = 0; i < 4; i++) {
                o0 += xp3[i][0]; o1 += xp3[i][1]; o2 += xp3[i][2];
            }
            // stage-4: width-1 softmax -> p==1, entropy==0 in fp32
            float reg = shXp[144] / (float)NN + ent2 / 48.f + ent3 / 12.f;
            out[0] = o0; out[1] = o1; out[2] = o2; out[3] = reg;
        }
    }
}

extern "C" void kernel_launch(void* const* d_in, const int* in_sizes, int n_in,
                              void* d_out, int out_size, void* d_ws, size_t ws_size,
                              hipStream_t stream) {
    const float* x  = (const float*)d_in[0];
    const int*   ei = (const int*)d_in[1];
    const float* ea = (const float*)d_in[2];
    // d_in[3] = adj — unused by the reference.
    const float* W1 = (const float*)d_in[4];
    const float* b1 = (const float*)d_in[5];
    const float* W2 = (const float*)d_in[6];
    const float* b2 = (const float*)d_in[7];
    const float* P1 = (const float*)d_in[8];
    const float* P2 = (const float*)d_in[9];
    const float* P3 = (const float*)d_in[10];
    // d_in[11] = P4 — width-1 softmax, handled analytically.
    const int* src = ei;
    const int* dst = ei + EE;
    float* ws  = (float*)d_ws;
    float* out = (float*)d_out;

    k1_deg_xw<<<SB, NTHR, 0, stream>>>(dst, ea, x, W1, ws);
    k2_dinv<<<RB, NTHR, 0, stream>>>(ws);
    k_scat<<<SB, NTHR, 0, stream>>>(src, dst, ea, ws + OFF_U0, ws);
    k_red_conv<<<RB, NTHR, 0, stream>>>(ws + OFF_XW, nullptr, b1,
                                        ws + OFF_C1, ws + OFF_U1, ws);
    k_scat<<<SB, NTHR, 0, stream>>>(src, dst, ea, ws + OFF_U1, ws);
    k_red_conv<<<RB, NTHR, 0, stream>>>(ws + OFF_C1, W2, b2,
                                        ws + OFF_C2, ws + OFF_U2, ws);
    k_scat<<<SB, NTHR, 0, stream>>>(src, dst, ea, ws + OFF_U2, ws);
    k8_final<<<RB, NTHR, 0, stream>>>(ws + OFF_C2, W2, b2,
                                      ws + OFF_C1, ws + OFF_C2,
                                      P1, P2, P3, ws, out);
}